// Round 1
// baseline (443.542 us; speedup 1.0000x reference)
//
#include <hip/hip_runtime.h>

// Problem constants (from reference): N=8, H=32, L=512, S=512, MAX_SPATIAL=100
#define NN 8
#define HH 32
#define LL 512
#define SS 512
#define MAXP 100

// LS/4 = 512*512/4 = 65536 float4-units per (n) slice of [L,S]
#define LS4 65536

__global__ __launch_bounds__(256) void gpe_kernel(
    const float* __restrict__ QK,
    const int*   __restrict__ pos,
    const float* __restrict__ emb,
    float*       __restrict__ out)
{
    // Table staged transposed: tbl[h*MAXP + p] = emb[p*H + h], row p==0 zeroed.
    // [h][p] layout: within a wave h is uniform, p is ~random in [0,100) ->
    // banks spread; ~2-way aliasing on average (free on gfx950).
    __shared__ float tbl[HH * MAXP];
    const int tid = threadIdx.x;
    for (int idx = tid; idx < HH * MAXP; idx += 256) {
        const int p = idx / HH;
        const int h = idx - p * HH;
        const float v = (p == 0) ? 0.0f : emb[p * HH + h];
        tbl[h * MAXP + p] = v;
    }
    __syncthreads();

    // One thread per 4 consecutive s of one (n,l); loops over all H heads so
    // pos is read exactly once from HBM.
    const int vecId = blockIdx.x * 256 + tid;      // 0 .. N*L*S/4 - 1
    const int n   = vecId >> 16;                   // / LS4
    const int ls4 = vecId & (LS4 - 1);

    const int4 p4 = ((const int4*)pos)[vecId];

    const float4* __restrict__ qk4  = (const float4*)QK;
    float4*       __restrict__ out4 = (float4*)out;

    // base index in float4 units; max = 7*32*65536 + 31*65536 + 65535 < 2^24
    int idx4 = n * (HH * LS4) + ls4;

#pragma unroll 4
    for (int h = 0; h < HH; ++h, idx4 += LS4) {
        const float* th = &tbl[h * MAXP];
        float4 q = qk4[idx4];
        q.x += th[p4.x];
        q.y += th[p4.y];
        q.z += th[p4.z];
        q.w += th[p4.w];
        out4[idx4] = q;
    }
}

extern "C" void kernel_launch(void* const* d_in, const int* in_sizes, int n_in,
                              void* d_out, int out_size, void* d_ws, size_t ws_size,
                              hipStream_t stream) {
    const float* QK  = (const float*)d_in[0];
    const int*   pos = (const int*)d_in[1];
    const float* emb = (const float*)d_in[2];
    float*       out = (float*)d_out;

    // N*L*S/4 threads = 524288 -> 2048 blocks of 256
    const int total_vec = (NN * LL * SS) / 4;
    const int block = 256;
    const int grid = total_vec / block;
    gpe_kernel<<<grid, block, 0, stream>>>(QK, pos, emb, out);
}